// Round 10
// baseline (12981.125 us; speedup 1.0000x reference)
//
#include <hip/hip_runtime.h>
#include <math.h>

#define NFFT   1024
#define NH     512
#define HOP    64
#define NMELS  80
#define NFR    512
#define NBINS  513
#define NITER  300
#define SIGLEN 33728
#define NSEG   527
#define NT     256
#define NB     512

// ---- workspace layout (4B units) ----
#define TBL_WIN  0          // win[1024]
#define TBL_TWR  1024       // twr[256]
#define TBL_TWI  1280       // twi[256]
#define TBL_W1R  1536       // w1r[513]
#define TBL_W1I  2056       // w1i[513]
#define OFF_MAG  4096       // mag[512*513]
#define OFF_IWS  266752     // iws[33728]
#define OFF_F    300480     // F[512*1024]
#define OFF_X    824768     // x[33792]
#define FLAG_F   858560     // int fflag[512]
#define FLAG_S   859072     // int sflag[512]

typedef unsigned long long u64;
typedef unsigned int u32;

// ---- coherent (agent-scope sc1) accessors ----
__device__ __forceinline__ float4 coh_load4(const float* p) {
    u64 a = __hip_atomic_load((const u64*)p,       __ATOMIC_RELAXED, __HIP_MEMORY_SCOPE_AGENT);
    u64 b = __hip_atomic_load((const u64*)(p + 2), __ATOMIC_RELAXED, __HIP_MEMORY_SCOPE_AGENT);
    float2 fa, fb;
    __builtin_memcpy(&fa, &a, 8);
    __builtin_memcpy(&fb, &b, 8);
    return make_float4(fa.x, fa.y, fb.x, fb.y);
}
__device__ __forceinline__ void coh_store4(float* p, float4 v) {
    float2 fa = make_float2(v.x, v.y), fb = make_float2(v.z, v.w);
    u64 a, b;
    __builtin_memcpy(&a, &fa, 8);
    __builtin_memcpy(&b, &fb, 8);
    __hip_atomic_store((u64*)p,       a, __ATOMIC_RELAXED, __HIP_MEMORY_SCOPE_AGENT);
    __hip_atomic_store((u64*)(p + 2), b, __ATOMIC_RELAXED, __HIP_MEMORY_SCOPE_AGENT);
}
__device__ __forceinline__ float coh_load1(const float* p) {
    u32 a = __hip_atomic_load((const u32*)p, __ATOMIC_RELAXED, __HIP_MEMORY_SCOPE_AGENT);
    float f;
    __builtin_memcpy(&f, &a, 4);
    return f;
}
__device__ __forceinline__ void coh_store1(float* p, float v) {
    u32 a;
    __builtin_memcpy(&a, &v, 4);
    __hip_atomic_store((u32*)p, a, __ATOMIC_RELAXED, __HIP_MEMORY_SCOPE_AGENT);
}

// ---- radix-4 Stockham stage (verified), caller guards tid<128 ----
template<int P, int SH, bool INV>
__device__ __forceinline__ void r4b(const float* __restrict__ sR, const float* __restrict__ sI,
                                    float* __restrict__ dR, float* __restrict__ dI,
                                    const float* twr, const float* twi, int j) {
    int k  = j & (P - 1);
    int d0 = ((j - k) << 2) + k;
    float x0r = sR[j],       x0i = sI[j];
    float x1r = sR[j + 128], x1i = sI[j + 128];
    float x2r = sR[j + 256], x2i = sI[j + 256];
    float x3r = sR[j + 384], x3i = sI[j + 384];
    int tb = k << SH;
    float c1 = twr[tb], s1 = twi[tb];
    if (INV) s1 = -s1;
    float c2 = c1 * c1 - s1 * s1, s2 = 2.f * c1 * s1;
    float c3 = c1 * c2 - s1 * s2, s3 = c1 * s2 + s1 * c2;
    float a1r = x1r * c1 - x1i * s1, a1i = x1r * s1 + x1i * c1;
    float a2r = x2r * c2 - x2i * s2, a2i = x2r * s2 + x2i * c2;
    float a3r = x3r * c3 - x3i * s3, a3i = x3r * s3 + x3i * c3;
    float t0r = x0r + a2r, t0i = x0i + a2i;
    float t1r = x0r - a2r, t1i = x0i - a2i;
    float t2r = a1r + a3r, t2i = a1i + a3i;
    float t3r = a1r - a3r, t3i = a1i - a3i;
    float i3r = INV ? -t3i : t3i;
    float i3i = INV ?  t3r : -t3r;
    dR[d0]         = t0r + t2r;  dI[d0]         = t0i + t2i;
    dR[d0 + P]     = t1r + i3r;  dI[d0 + P]     = t1i + i3i;
    dR[d0 + 2 * P] = t0r - t2r;  dI[d0 + 2 * P] = t0i - t2i;
    dR[d0 + 3 * P] = t1r - i3r;  dI[d0 + 3 * P] = t1i - i3i;
}

// ================= k_init (round-6 verified, incl. flag zeroing) =============
struct __align__(16) SMemI {
    float xb[NFFT];
    float C0r[NH], C0i[NH];
    float C1r[NH], C1i[NH];
    float win[NFFT];
    float twr[256], twi[256];
    float mag[516];
};

extern "C" __global__ __launch_bounds__(NT)
void k_init(const float* __restrict__ mel,
            const float* __restrict__ invmel,
            float* __restrict__ ws) {
    __shared__ SMemI sm;
    const int tid = threadIdx.x;
    const int t   = blockIdx.x;

    for (int n = tid; n < NFFT; n += NT) {
        double a = (2.0 * 3.14159265358979323846) * (double)n / 1024.0;
        sm.win[n] = (float)(0.5 - 0.5 * cos(a));
    }
    for (int j = tid; j < 256; j += NT) {
        double a = (2.0 * 3.14159265358979323846) * (double)j / 512.0;
        sm.twr[j] = (float)cos(a);
        sm.twi[j] = (float)(-sin(a));
    }
    __syncthreads();
    if (t == 0) {
        for (int n = tid; n < NFFT; n += NT) ws[TBL_WIN + n] = sm.win[n];
        for (int j = tid; j < 256; j += NT) {
            ws[TBL_TWR + j] = sm.twr[j];
            ws[TBL_TWI + j] = sm.twi[j];
        }
        for (int k = tid; k < NBINS; k += NT) {
            double a = (2.0 * 3.14159265358979323846) * (double)k / 1024.0;
            ws[TBL_W1R + k] = (float)cos(a);
            ws[TBL_W1I + k] = (float)sin(a);
        }
        ((int*)ws)[FLAG_F + tid]       = 0;
        ((int*)ws)[FLAG_F + 256 + tid] = 0;
        ((int*)ws)[FLAG_S + tid]       = 0;
        ((int*)ws)[FLAG_S + 256 + tid] = 0;
    }

    for (int p = t * NT + tid; p < SIGLEN; p += NFR * NT) {
        int tq = p >> 6, io = p & 63;
        float s = 0.f;
#pragma unroll
        for (int m = 0; m < 16; ++m) {
            int tp = tq - m;
            if (tp >= 0 && tp < NFR) {
                float w = sm.win[io + (m << 6)];
                s += w * w;
            }
        }
        ws[OFF_IWS + p] = (s > 1e-11f) ? (1.0f / s) : 1.0f;
    }

    if (tid < NMELS) sm.xb[tid] = exp10f(mel[tid * NFR + t]);
    __syncthreads();
    for (int k = tid; k < NBINS; k += NT) {
        const float* row = invmel + k * NMELS;
        float s = 0.f;
#pragma unroll 8
        for (int j = 0; j < NMELS; ++j) s += row[j] * sm.xb[j];
        ws[OFF_MAG + t * NBINS + k] = s;
        sm.mag[k] = s;
    }
    __syncthreads();

    for (int k = tid; k < NH; k += NT) {
        float xr = sm.mag[k], yr = sm.mag[512 - k];
        double a = (2.0 * 3.14159265358979323846) * (double)k / 1024.0;
        float c = (float)cos(a), s = (float)sin(a);
        float dr = xr - yr;
        sm.C1r[k] = ((xr + yr) - s * dr) * (1.0f / 1024.0f);
        sm.C1i[k] = (c * dr) * (1.0f / 1024.0f);
    }
    __syncthreads();
    if (tid < 128) {
        float x0r = sm.C1r[tid],       x0i = sm.C1i[tid];
        float x1r = sm.C1r[tid + 128], x1i = sm.C1i[tid + 128];
        float x2r = sm.C1r[tid + 256], x2i = sm.C1i[tid + 256];
        float x3r = sm.C1r[tid + 384], x3i = sm.C1i[tid + 384];
        float t0r = x0r + x2r, t0i = x0i + x2i;
        float t1r = x0r - x2r, t1i = x0i - x2i;
        float t2r = x1r + x3r, t2i = x1i + x3i;
        float t3r = x1r - x3r, t3i = x1i - x3i;
        float4 vr = make_float4(t0r + t2r, t1r - t3i, t0r - t2r, t1r + t3i);
        float4 vi = make_float4(t0i + t2i, t1i + t3r, t0i - t2i, t1i - t3r);
        ((float4*)sm.C0r)[tid] = vr;
        ((float4*)sm.C0i)[tid] = vi;
    }
    __syncthreads();
    if (tid < 128) r4b<4, 5, true>(sm.C0r, sm.C0i, sm.C1r, sm.C1i, sm.twr, sm.twi, tid);
    __syncthreads();
    if (tid < 128) r4b<16, 3, true>(sm.C1r, sm.C1i, sm.C0r, sm.C0i, sm.twr, sm.twi, tid);
    __syncthreads();
    if (tid < 128) r4b<64, 1, true>(sm.C0r, sm.C0i, sm.C1r, sm.C1i, sm.twr, sm.twi, tid);
    __syncthreads();
    {
        float c = sm.twr[tid], s = -sm.twi[tid];
        float x0r = sm.C1r[tid], x0i = sm.C1i[tid];
        float x1r = sm.C1r[tid + 256], x1i = sm.C1i[tid + 256];
        float ar = x1r * c - x1i * s, ai = x1r * s + x1i * c;
        sm.C0r[tid]       = x0r + ar;  sm.C0i[tid]       = x0i + ai;
        sm.C0r[tid + 256] = x0r - ar;  sm.C0i[tid + 256] = x0i - ai;
    }
    __syncthreads();

    float4 w4 = ((float4*)sm.win)[tid];
    float4 o;
    o.x = w4.x * sm.C0r[2 * tid];
    o.y = w4.y * sm.C0i[2 * tid];
    o.z = w4.z * sm.C0r[2 * tid + 1];
    o.w = w4.w * sm.C0i[2 * tid + 1];
    *(float4*)&ws[OFF_F + (t << 10) + (tid << 2)] = o;
}

// ====== persistent Griffin-Lim: neighbor flags, release/acquire sync ========
struct __align__(16) SM1 {
    float C0r[NH], C0i[NH];
    float C1r[NH], C1i[NH];
    float twr[256], twi[256];
};

extern "C" __global__ __launch_bounds__(NT)
void k_persist(float* __restrict__ ws, float* __restrict__ out) {
    __shared__ SM1 sm;
    const int tid = threadIdx.x;
    const int t   = blockIdx.x;       // frame owned
    const int i0  = tid << 2;
    const int j2  = 512 - tid;
    const int n0  = tid << 1;

    const float* tbl  = ws;
    const float* magg = ws + OFF_MAG;
    const float* iws  = ws + OFF_IWS;
    float* F  = ws + OFF_F;
    float* X  = ws + OFF_X;
    int* ffl  = (int*)ws + FLAG_F;
    int* sfl  = (int*)ws + FLAG_S;

    // ---- one-time staging ----
    if (tid < 64)       ((float4*)sm.twr)[tid]      = ((const float4*)(tbl + TBL_TWR))[tid];
    else if (tid < 128) ((float4*)sm.twi)[tid - 64] = ((const float4*)(tbl + TBL_TWI))[tid - 64];

    float4 w4 = ((const float4*)(tbl + TBL_WIN))[tid];
    float m_a, m_b, m_ny = 0.f, w1r_a, w1i_a, w1r_b, w1i_b;
    {
        const int s0 = t * NBINS;
        if (tid == 0) {
            m_a = magg[s0]; m_ny = magg[s0 + 512]; m_b = magg[s0 + 256];
            w1r_a = 1.f; w1i_a = 0.f; w1r_b = 0.f; w1i_b = 1.f;
        } else {
            m_a = magg[s0 + tid]; m_b = magg[s0 + j2];
            w1r_a = tbl[TBL_W1R + tid]; w1i_a = tbl[TBL_W1I + tid];
            w1r_b = tbl[TBL_W1R + j2];  w1i_b = tbl[TBL_W1I + j2];
        }
    }
    // segment ownership: seg t (lanes 0..63); blocks >=497 also seg t+15 (lanes 64..127)
    const bool extra = (t >= 497);
    int gseg = -1;
    if (tid < 64) gseg = t;
    else if (tid < 128 && extra) gseg = t + 15;
    const int u = tid & 63;
    float iwreg = 0.f;
    if (gseg >= 0) iwreg = iws[(gseg << 6) + u];

    // wait windows (audited 3x: cover all producers AND all WAR readers)
    const int loA = extra ? 497 : t;
    const int hiA = (t + 15 < 511) ? (t + 15) : 511;
    const int loB = (t >= 15) ? (t - 15) : 0;
    const int hiB = extra ? 511 : t;

    // ---- prologue: x^0 segment(s) from k_init frames ----
    if (gseg >= 0) {
        float acc = 0.f;
#pragma unroll
        for (int m = 0; m < 16; ++m) {
            int tp = gseg - m;
            if (tp >= 0 && tp < NFR)
                acc += coh_load1(&F[(tp << 10) + u + (m << 6)]);
        }
        coh_store1(&X[(gseg << 6) + u], acc * iwreg);
    }
    __syncthreads();   // all block's X stores issued & drained (vmcnt at barrier)
    if (tid == 0)
        __hip_atomic_store(sfl + t, 1, __ATOMIC_RELEASE, __HIP_MEMORY_SCOPE_AGENT);

#pragma unroll 1
    for (int it = 1; it <= NITER; ++it) {
        // ===== phase A: wait x^{it-1} window, stft+proj+istft, write frame =====
        if (tid <= hiA - loA) {
            const int* f = sfl + loA + tid;
            while (__hip_atomic_load(f, __ATOMIC_RELAXED, __HIP_MEMORY_SCOPE_AGENT) < it)
                __builtin_amdgcn_s_sleep(1);
        }
        __syncthreads();
        __builtin_amdgcn_fence(__ATOMIC_ACQUIRE, "agent");   // inv stale lines before X reads

        {   // x window * win -> packed z in C1
            float4 xv = coh_load4(&X[(t << 6) + i0]);
            sm.C1r[n0]     = xv.x * w4.x;
            sm.C1i[n0]     = xv.y * w4.y;
            sm.C1r[n0 + 1] = xv.z * w4.z;
            sm.C1i[n0 + 1] = xv.w * w4.w;
        }
        __syncthreads();
        // forward FFT: C1 -> C0
        if (tid < 128) {
            float x0r = sm.C1r[tid],       x0i = sm.C1i[tid];
            float x1r = sm.C1r[tid + 128], x1i = sm.C1i[tid + 128];
            float x2r = sm.C1r[tid + 256], x2i = sm.C1i[tid + 256];
            float x3r = sm.C1r[tid + 384], x3i = sm.C1i[tid + 384];
            float t0r = x0r + x2r, t0i = x0i + x2i;
            float t1r = x0r - x2r, t1i = x0i - x2i;
            float t2r = x1r + x3r, t2i = x1i + x3i;
            float t3r = x1r - x3r, t3i = x1i - x3i;
            float4 vr = make_float4(t0r + t2r, t1r + t3i, t0r - t2r, t1r - t3i);
            float4 vi = make_float4(t0i + t2i, t1i - t3r, t0i - t2i, t1i + t3r);
            ((float4*)sm.C0r)[tid] = vr;
            ((float4*)sm.C0i)[tid] = vi;
        }
        __syncthreads();
        if (tid < 128) r4b<4, 5, false>(sm.C0r, sm.C0i, sm.C1r, sm.C1i, sm.twr, sm.twi, tid);
        __syncthreads();
        if (tid < 128) r4b<16, 3, false>(sm.C1r, sm.C1i, sm.C0r, sm.C0i, sm.twr, sm.twi, tid);
        __syncthreads();
        if (tid < 128) r4b<64, 1, false>(sm.C0r, sm.C0i, sm.C1r, sm.C1i, sm.twr, sm.twi, tid);
        __syncthreads();
        {
            float c = sm.twr[tid], s = sm.twi[tid];
            float x0r = sm.C1r[tid], x0i = sm.C1i[tid];
            float x1r = sm.C1r[tid + 256], x1i = sm.C1i[tid + 256];
            float ar = x1r * c - x1i * s, ai = x1r * s + x1i * c;
            sm.C0r[tid]       = x0r + ar;  sm.C0i[tid]       = x0i + ai;
            sm.C0r[tid + 256] = x0r - ar;  sm.C0i[tid + 256] = x0i - ai;
        }
        __syncthreads();

        // fused unpack + phase projection + iFFT prep: C0 -> C1
        if (tid == 0) {
            float zr = sm.C0r[0], zi = sm.C0i[0];
            float e0 = zr + zi;
            float e5 = zr - zi;
            float X0 = m_a  * e0 / fmaxf(1e-8f, fabsf(e0));
            float X5 = m_ny * e5 / fmaxf(1e-8f, fabsf(e5));
            sm.C1r[0] = (X0 + X5) * (1.0f / 1024.0f);
            sm.C1i[0] = (X0 - X5) * (1.0f / 1024.0f);
            float z6r = sm.C0r[256], z6i = sm.C0i[256];
            float sc6 = m_b / fmaxf(1e-8f, sqrtf(z6r * z6r + z6i * z6i));
            float X6r = z6r * sc6, X6i = -z6i * sc6;
            sm.C1r[256] = X6r * (2.0f / 1024.0f);
            sm.C1i[256] = -X6i * (2.0f / 1024.0f);
        } else {
            float zr = sm.C0r[tid], zi = sm.C0i[tid];
            float ur = sm.C0r[j2],  ui = sm.C0i[j2];
            float er = 0.5f * (zr + ur), ei = 0.5f * (zi - ui);
            float dr = zr - ur,          di = zi + ui;
            float odr = 0.5f * di, odi = -0.5f * dr;
            float e1r = er + w1r_a * odr + w1i_a * odi;
            float e1i = ei + w1r_a * odi - w1i_a * odr;
            float e2r =  er + w1r_b * odr - w1i_b * odi;
            float e2i = -ei - w1r_b * odi - w1i_b * odr;
            float sc1 = m_a / fmaxf(1e-8f, sqrtf(e1r * e1r + e1i * e1i));
            float sc2 = m_b / fmaxf(1e-8f, sqrtf(e2r * e2r + e2i * e2i));
            float X1r = e1r * sc1, X1i = e1i * sc1;
            float X2r = e2r * sc2, X2i = e2i * sc2;
            float Er = X1r + X2r, Ei = X1i - X2i;
            float Dr = X1r - X2r, Di = X1i + X2i;
            float wdr = w1r_a * Dr - w1i_a * Di, wdi = w1r_a * Di + w1i_a * Dr;
            sm.C1r[tid] = (Er - wdi) * (1.0f / 1024.0f);
            sm.C1i[tid] = (Ei + wdr) * (1.0f / 1024.0f);
            float wdr2 = -w1r_b * Dr - w1i_b * Di, wdi2 = w1r_b * Di - w1i_b * Dr;
            sm.C1r[j2] = (Er - wdi2) * (1.0f / 1024.0f);
            sm.C1i[j2] = (-Ei + wdr2) * (1.0f / 1024.0f);
        }
        __syncthreads();

        // inverse FFT: C1 -> C0
        if (tid < 128) {
            float x0r = sm.C1r[tid],       x0i = sm.C1i[tid];
            float x1r = sm.C1r[tid + 128], x1i = sm.C1i[tid + 128];
            float x2r = sm.C1r[tid + 256], x2i = sm.C1i[tid + 256];
            float x3r = sm.C1r[tid + 384], x3i = sm.C1i[tid + 384];
            float t0r = x0r + x2r, t0i = x0i + x2i;
            float t1r = x0r - x2r, t1i = x0i - x2i;
            float t2r = x1r + x3r, t2i = x1i + x3i;
            float t3r = x1r - x3r, t3i = x1i - x3i;
            float4 vr = make_float4(t0r + t2r, t1r - t3i, t0r - t2r, t1r + t3i);
            float4 vi = make_float4(t0i + t2i, t1i + t3r, t0i - t2i, t1i - t3r);
            ((float4*)sm.C0r)[tid] = vr;
            ((float4*)sm.C0i)[tid] = vi;
        }
        __syncthreads();
        if (tid < 128) r4b<4, 5, true>(sm.C0r, sm.C0i, sm.C1r, sm.C1i, sm.twr, sm.twi, tid);
        __syncthreads();
        if (tid < 128) r4b<16, 3, true>(sm.C1r, sm.C1i, sm.C0r, sm.C0i, sm.twr, sm.twi, tid);
        __syncthreads();
        if (tid < 128) r4b<64, 1, true>(sm.C0r, sm.C0i, sm.C1r, sm.C1i, sm.twr, sm.twi, tid);
        __syncthreads();
        {
            float c = sm.twr[tid], s = -sm.twi[tid];
            float x0r = sm.C1r[tid], x0i = sm.C1i[tid];
            float x1r = sm.C1r[tid + 256], x1i = sm.C1i[tid + 256];
            float ar = x1r * c - x1i * s, ai = x1r * s + x1i * c;
            sm.C0r[tid]       = x0r + ar;  sm.C0i[tid]       = x0i + ai;
            sm.C0r[tid + 256] = x0r - ar;  sm.C0i[tid + 256] = x0i - ai;
        }
        __syncthreads();

        // store windowed frame (sc1)
        {
            float4 o;
            o.x = w4.x * sm.C0r[n0];
            o.y = w4.y * sm.C0i[n0];
            o.z = w4.z * sm.C0r[n0 + 1];
            o.w = w4.w * sm.C0i[n0 + 1];
            coh_store4(&F[(t << 10) + i0], o);
        }
        __syncthreads();   // whole block's F stores drained
        if (tid == 0)
            __hip_atomic_store(ffl + t, it, __ATOMIC_RELEASE, __HIP_MEMORY_SCOPE_AGENT);

        // ===== phase B: wait frame^{it} window, OLA own segment(s) =====
        if (tid <= hiB - loB) {
            const int* f = ffl + loB + tid;
            while (__hip_atomic_load(f, __ATOMIC_RELAXED, __HIP_MEMORY_SCOPE_AGENT) < it)
                __builtin_amdgcn_s_sleep(1);
        }
        __syncthreads();
        __builtin_amdgcn_fence(__ATOMIC_ACQUIRE, "agent");   // inv stale lines before F reads

        if (gseg >= 0) {
            float acc = 0.f;
#pragma unroll
            for (int m = 0; m < 16; ++m) {
                int tp = gseg - m;
                if (tp >= 0 && tp < NFR)
                    acc += coh_load1(&F[(tp << 10) + u + (m << 6)]);
            }
            float val = acc * iwreg;
            if (it < NITER) coh_store1(&X[(gseg << 6) + u], val);
            else            out[(gseg << 6) + u] = val;
        }
        __syncthreads();   // block's X stores drained
        if (tid == 0 && it < NITER)
            __hip_atomic_store(sfl + t, it + 1, __ATOMIC_RELEASE, __HIP_MEMORY_SCOPE_AGENT);
    }
}

extern "C" void kernel_launch(void* const* d_in, const int* in_sizes, int n_in,
                              void* d_out, int out_size, void* d_ws, size_t ws_size,
                              hipStream_t stream) {
    const float* mel    = (const float*)d_in[0];
    const float* invmel = (const float*)d_in[1];
    float* out = (float*)d_out;
    float* ws  = (float*)d_ws;

    k_init<<<NFR, NT, 0, stream>>>(mel, invmel, ws);
    k_persist<<<NB, NT, 0, stream>>>(ws, out);
}

// Round 11
// 6854.898 us; speedup vs baseline: 1.8937x; 1.8937x over previous
//
#include <hip/hip_runtime.h>
#include <math.h>

#define NFFT   1024
#define NH     512
#define HOP    64
#define NMELS  80
#define NFR    512
#define NBINS  513
#define NITER  300
#define SIGLEN 33728
#define NSEG   527
#define NT     256
#define NB     512

// ---- workspace layout (4B units) ----
#define TBL_WIN  0          // win[1024]
#define TBL_TWR  1024       // twr[256]
#define TBL_TWI  1280       // twi[256]
#define TBL_W1R  1536       // w1r[513]
#define TBL_W1I  2056       // w1i[513]
#define OFF_MAG  4096       // mag[512*513]
#define OFF_IWS  266752     // iws[33728]
#define OFF_F    300480     // F[512*1024]
#define OFF_X    824768     // x[33792]
#define FLAG_F   858560     // int fflag[512]
#define FLAG_S   859072     // int sflag[512]

typedef unsigned long long u64;
typedef unsigned int u32;

// ---- coherent (agent-scope sc1) accessors ----
__device__ __forceinline__ float4 coh_load4(const float* p) {
    u64 a = __hip_atomic_load((const u64*)p,       __ATOMIC_RELAXED, __HIP_MEMORY_SCOPE_AGENT);
    u64 b = __hip_atomic_load((const u64*)(p + 2), __ATOMIC_RELAXED, __HIP_MEMORY_SCOPE_AGENT);
    float2 fa, fb;
    __builtin_memcpy(&fa, &a, 8);
    __builtin_memcpy(&fb, &b, 8);
    return make_float4(fa.x, fa.y, fb.x, fb.y);
}
__device__ __forceinline__ void coh_store4(float* p, float4 v) {
    float2 fa = make_float2(v.x, v.y), fb = make_float2(v.z, v.w);
    u64 a, b;
    __builtin_memcpy(&a, &fa, 8);
    __builtin_memcpy(&b, &fb, 8);
    __hip_atomic_store((u64*)p,       a, __ATOMIC_RELAXED, __HIP_MEMORY_SCOPE_AGENT);
    __hip_atomic_store((u64*)(p + 2), b, __ATOMIC_RELAXED, __HIP_MEMORY_SCOPE_AGENT);
}
__device__ __forceinline__ float coh_load1(const float* p) {
    u32 a = __hip_atomic_load((const u32*)p, __ATOMIC_RELAXED, __HIP_MEMORY_SCOPE_AGENT);
    float f;
    __builtin_memcpy(&f, &a, 4);
    return f;
}
__device__ __forceinline__ void coh_store1(float* p, float v) {
    u32 a;
    __builtin_memcpy(&a, &v, 4);
    __hip_atomic_store((u32*)p, a, __ATOMIC_RELAXED, __HIP_MEMORY_SCOPE_AGENT);
}

// ---- radix-4 Stockham stage (verified), caller guards tid<128 ----
template<int P, int SH, bool INV>
__device__ __forceinline__ void r4b(const float* __restrict__ sR, const float* __restrict__ sI,
                                    float* __restrict__ dR, float* __restrict__ dI,
                                    const float* twr, const float* twi, int j) {
    int k  = j & (P - 1);
    int d0 = ((j - k) << 2) + k;
    float x0r = sR[j],       x0i = sI[j];
    float x1r = sR[j + 128], x1i = sI[j + 128];
    float x2r = sR[j + 256], x2i = sI[j + 256];
    float x3r = sR[j + 384], x3i = sI[j + 384];
    int tb = k << SH;
    float c1 = twr[tb], s1 = twi[tb];
    if (INV) s1 = -s1;
    float c2 = c1 * c1 - s1 * s1, s2 = 2.f * c1 * s1;
    float c3 = c1 * c2 - s1 * s2, s3 = c1 * s2 + s1 * c2;
    float a1r = x1r * c1 - x1i * s1, a1i = x1r * s1 + x1i * c1;
    float a2r = x2r * c2 - x2i * s2, a2i = x2r * s2 + x2i * c2;
    float a3r = x3r * c3 - x3i * s3, a3i = x3r * s3 + x3i * c3;
    float t0r = x0r + a2r, t0i = x0i + a2i;
    float t1r = x0r - a2r, t1i = x0i - a2i;
    float t2r = a1r + a3r, t2i = a1i + a3i;
    float t3r = a1r - a3r, t3i = a1i - a3i;
    float i3r = INV ? -t3i : t3i;
    float i3i = INV ?  t3r : -t3r;
    dR[d0]         = t0r + t2r;  dI[d0]         = t0i + t2i;
    dR[d0 + P]     = t1r + i3r;  dI[d0 + P]     = t1i + i3i;
    dR[d0 + 2 * P] = t0r - t2r;  dI[d0 + 2 * P] = t0i - t2i;
    dR[d0 + 3 * P] = t1r - i3r;  dI[d0 + 3 * P] = t1i - i3i;
}

// ================= k_init (round-6 verified, incl. flag zeroing) =============
struct __align__(16) SMemI {
    float xb[NFFT];
    float C0r[NH], C0i[NH];
    float C1r[NH], C1i[NH];
    float win[NFFT];
    float twr[256], twi[256];
    float mag[516];
};

extern "C" __global__ __launch_bounds__(NT)
void k_init(const float* __restrict__ mel,
            const float* __restrict__ invmel,
            float* __restrict__ ws) {
    __shared__ SMemI sm;
    const int tid = threadIdx.x;
    const int t   = blockIdx.x;

    for (int n = tid; n < NFFT; n += NT) {
        double a = (2.0 * 3.14159265358979323846) * (double)n / 1024.0;
        sm.win[n] = (float)(0.5 - 0.5 * cos(a));
    }
    for (int j = tid; j < 256; j += NT) {
        double a = (2.0 * 3.14159265358979323846) * (double)j / 512.0;
        sm.twr[j] = (float)cos(a);
        sm.twi[j] = (float)(-sin(a));
    }
    __syncthreads();
    if (t == 0) {
        for (int n = tid; n < NFFT; n += NT) ws[TBL_WIN + n] = sm.win[n];
        for (int j = tid; j < 256; j += NT) {
            ws[TBL_TWR + j] = sm.twr[j];
            ws[TBL_TWI + j] = sm.twi[j];
        }
        for (int k = tid; k < NBINS; k += NT) {
            double a = (2.0 * 3.14159265358979323846) * (double)k / 1024.0;
            ws[TBL_W1R + k] = (float)cos(a);
            ws[TBL_W1I + k] = (float)sin(a);
        }
        ((int*)ws)[FLAG_F + tid]       = 0;
        ((int*)ws)[FLAG_F + 256 + tid] = 0;
        ((int*)ws)[FLAG_S + tid]       = 0;
        ((int*)ws)[FLAG_S + 256 + tid] = 0;
    }

    for (int p = t * NT + tid; p < SIGLEN; p += NFR * NT) {
        int tq = p >> 6, io = p & 63;
        float s = 0.f;
#pragma unroll
        for (int m = 0; m < 16; ++m) {
            int tp = tq - m;
            if (tp >= 0 && tp < NFR) {
                float w = sm.win[io + (m << 6)];
                s += w * w;
            }
        }
        ws[OFF_IWS + p] = (s > 1e-11f) ? (1.0f / s) : 1.0f;
    }

    if (tid < NMELS) sm.xb[tid] = exp10f(mel[tid * NFR + t]);
    __syncthreads();
    for (int k = tid; k < NBINS; k += NT) {
        const float* row = invmel + k * NMELS;
        float s = 0.f;
#pragma unroll 8
        for (int j = 0; j < NMELS; ++j) s += row[j] * sm.xb[j];
        ws[OFF_MAG + t * NBINS + k] = s;
        sm.mag[k] = s;
    }
    __syncthreads();

    for (int k = tid; k < NH; k += NT) {
        float xr = sm.mag[k], yr = sm.mag[512 - k];
        double a = (2.0 * 3.14159265358979323846) * (double)k / 1024.0;
        float c = (float)cos(a), s = (float)sin(a);
        float dr = xr - yr;
        sm.C1r[k] = ((xr + yr) - s * dr) * (1.0f / 1024.0f);
        sm.C1i[k] = (c * dr) * (1.0f / 1024.0f);
    }
    __syncthreads();
    if (tid < 128) {
        float x0r = sm.C1r[tid],       x0i = sm.C1i[tid];
        float x1r = sm.C1r[tid + 128], x1i = sm.C1i[tid + 128];
        float x2r = sm.C1r[tid + 256], x2i = sm.C1i[tid + 256];
        float x3r = sm.C1r[tid + 384], x3i = sm.C1i[tid + 384];
        float t0r = x0r + x2r, t0i = x0i + x2i;
        float t1r = x0r - x2r, t1i = x0i - x2i;
        float t2r = x1r + x3r, t2i = x1i + x3i;
        float t3r = x1r - x3r, t3i = x1i - x3i;
        float4 vr = make_float4(t0r + t2r, t1r - t3i, t0r - t2r, t1r + t3i);
        float4 vi = make_float4(t0i + t2i, t1i + t3r, t0i - t2i, t1i - t3r);
        ((float4*)sm.C0r)[tid] = vr;
        ((float4*)sm.C0i)[tid] = vi;
    }
    __syncthreads();
    if (tid < 128) r4b<4, 5, true>(sm.C0r, sm.C0i, sm.C1r, sm.C1i, sm.twr, sm.twi, tid);
    __syncthreads();
    if (tid < 128) r4b<16, 3, true>(sm.C1r, sm.C1i, sm.C0r, sm.C0i, sm.twr, sm.twi, tid);
    __syncthreads();
    if (tid < 128) r4b<64, 1, true>(sm.C0r, sm.C0i, sm.C1r, sm.C1i, sm.twr, sm.twi, tid);
    __syncthreads();
    {
        float c = sm.twr[tid], s = -sm.twi[tid];
        float x0r = sm.C1r[tid], x0i = sm.C1i[tid];
        float x1r = sm.C1r[tid + 256], x1i = sm.C1i[tid + 256];
        float ar = x1r * c - x1i * s, ai = x1r * s + x1i * c;
        sm.C0r[tid]       = x0r + ar;  sm.C0i[tid]       = x0i + ai;
        sm.C0r[tid + 256] = x0r - ar;  sm.C0i[tid + 256] = x0i - ai;
    }
    __syncthreads();

    float4 w4 = ((float4*)sm.win)[tid];
    float4 o;
    o.x = w4.x * sm.C0r[2 * tid];
    o.y = w4.y * sm.C0i[2 * tid];
    o.z = w4.z * sm.C0r[2 * tid + 1];
    o.w = w4.w * sm.C0i[2 * tid + 1];
    *(float4*)&ws[OFF_F + (t << 10) + (tid << 2)] = o;
}

// ====== persistent Griffin-Lim: neighbor flags, RELEASE-only ordering =======
struct __align__(16) SM1 {
    float C0r[NH], C0i[NH];
    float C1r[NH], C1i[NH];
    float twr[256], twi[256];
};

extern "C" __global__ __launch_bounds__(NT)
void k_persist(float* __restrict__ ws, float* __restrict__ out) {
    __shared__ SM1 sm;
    const int tid = threadIdx.x;
    const int t   = blockIdx.x;       // frame owned
    const int i0  = tid << 2;
    const int j2  = 512 - tid;
    const int n0  = tid << 1;

    const float* tbl  = ws;
    const float* magg = ws + OFF_MAG;
    const float* iws  = ws + OFF_IWS;
    float* F  = ws + OFF_F;
    float* X  = ws + OFF_X;
    int* ffl  = (int*)ws + FLAG_F;
    int* sfl  = (int*)ws + FLAG_S;

    // ---- one-time staging ----
    if (tid < 64)       ((float4*)sm.twr)[tid]      = ((const float4*)(tbl + TBL_TWR))[tid];
    else if (tid < 128) ((float4*)sm.twi)[tid - 64] = ((const float4*)(tbl + TBL_TWI))[tid - 64];

    float4 w4 = ((const float4*)(tbl + TBL_WIN))[tid];
    float m_a, m_b, m_ny = 0.f, w1r_a, w1i_a, w1r_b, w1i_b;
    {
        const int s0 = t * NBINS;
        if (tid == 0) {
            m_a = magg[s0]; m_ny = magg[s0 + 512]; m_b = magg[s0 + 256];
            w1r_a = 1.f; w1i_a = 0.f; w1r_b = 0.f; w1i_b = 1.f;
        } else {
            m_a = magg[s0 + tid]; m_b = magg[s0 + j2];
            w1r_a = tbl[TBL_W1R + tid]; w1i_a = tbl[TBL_W1I + tid];
            w1r_b = tbl[TBL_W1R + j2];  w1i_b = tbl[TBL_W1I + j2];
        }
    }
    // segment ownership: seg t (lanes 0..63); blocks >=497 also seg t+15 (lanes 64..127)
    const bool extra = (t >= 497);
    int gseg = -1;
    if (tid < 64) gseg = t;
    else if (tid < 128 && extra) gseg = t + 15;
    const int u = tid & 63;
    float iwreg = 0.f;
    if (gseg >= 0) iwreg = iws[(gseg << 6) + u];

    // wait windows (audited 4x: cover all producers AND all WAR readers)
    const int loA = extra ? 497 : t;
    const int hiA = (t + 15 < 511) ? (t + 15) : 511;
    const int loB = (t >= 15) ? (t - 15) : 0;
    const int hiB = extra ? 511 : t;

    // ---- prologue: x^0 segment(s) from k_init frames ----
    if (gseg >= 0) {
        float acc = 0.f;
#pragma unroll
        for (int m = 0; m < 16; ++m) {
            int tp = gseg - m;
            if (tp >= 0 && tp < NFR)
                acc += coh_load1(&F[(tp << 10) + u + (m << 6)]);
        }
        coh_store1(&X[(gseg << 6) + u], acc * iwreg);
    }
    __syncthreads();   // all block's X stores issued
    if (tid == 0)
        __hip_atomic_store(sfl + t, 1, __ATOMIC_RELEASE, __HIP_MEMORY_SCOPE_AGENT);

#pragma unroll 1
    for (int it = 1; it <= NITER; ++it) {
        // ===== phase A: wait x^{it-1} window, stft+proj+istft, write frame =====
        if (tid <= hiA - loA) {
            const int* f = sfl + loA + tid;
            while (__hip_atomic_load(f, __ATOMIC_RELAXED, __HIP_MEMORY_SCOPE_AGENT) < it)
                __builtin_amdgcn_s_sleep(1);
        }
        __syncthreads();   // compiler barrier: no load hoisting above the wait

        {   // x window * win -> packed z in C1 (sc1 loads read L3 directly)
            float4 xv = coh_load4(&X[(t << 6) + i0]);
            sm.C1r[n0]     = xv.x * w4.x;
            sm.C1i[n0]     = xv.y * w4.y;
            sm.C1r[n0 + 1] = xv.z * w4.z;
            sm.C1i[n0 + 1] = xv.w * w4.w;
        }
        __syncthreads();
        // forward FFT: C1 -> C0
        if (tid < 128) {
            float x0r = sm.C1r[tid],       x0i = sm.C1i[tid];
            float x1r = sm.C1r[tid + 128], x1i = sm.C1i[tid + 128];
            float x2r = sm.C1r[tid + 256], x2i = sm.C1i[tid + 256];
            float x3r = sm.C1r[tid + 384], x3i = sm.C1i[tid + 384];
            float t0r = x0r + x2r, t0i = x0i + x2i;
            float t1r = x0r - x2r, t1i = x0i - x2i;
            float t2r = x1r + x3r, t2i = x1i + x3i;
            float t3r = x1r - x3r, t3i = x1i - x3i;
            float4 vr = make_float4(t0r + t2r, t1r + t3i, t0r - t2r, t1r - t3i);
            float4 vi = make_float4(t0i + t2i, t1i - t3r, t0i - t2i, t1i + t3r);
            ((float4*)sm.C0r)[tid] = vr;
            ((float4*)sm.C0i)[tid] = vi;
        }
        __syncthreads();
        if (tid < 128) r4b<4, 5, false>(sm.C0r, sm.C0i, sm.C1r, sm.C1i, sm.twr, sm.twi, tid);
        __syncthreads();
        if (tid < 128) r4b<16, 3, false>(sm.C1r, sm.C1i, sm.C0r, sm.C0i, sm.twr, sm.twi, tid);
        __syncthreads();
        if (tid < 128) r4b<64, 1, false>(sm.C0r, sm.C0i, sm.C1r, sm.C1i, sm.twr, sm.twi, tid);
        __syncthreads();
        {
            float c = sm.twr[tid], s = sm.twi[tid];
            float x0r = sm.C1r[tid], x0i = sm.C1i[tid];
            float x1r = sm.C1r[tid + 256], x1i = sm.C1i[tid + 256];
            float ar = x1r * c - x1i * s, ai = x1r * s + x1i * c;
            sm.C0r[tid]       = x0r + ar;  sm.C0i[tid]       = x0i + ai;
            sm.C0r[tid + 256] = x0r - ar;  sm.C0i[tid + 256] = x0i - ai;
        }
        __syncthreads();

        // fused unpack + phase projection + iFFT prep: C0 -> C1
        if (tid == 0) {
            float zr = sm.C0r[0], zi = sm.C0i[0];
            float e0 = zr + zi;
            float e5 = zr - zi;
            float X0 = m_a  * e0 / fmaxf(1e-8f, fabsf(e0));
            float X5 = m_ny * e5 / fmaxf(1e-8f, fabsf(e5));
            sm.C1r[0] = (X0 + X5) * (1.0f / 1024.0f);
            sm.C1i[0] = (X0 - X5) * (1.0f / 1024.0f);
            float z6r = sm.C0r[256], z6i = sm.C0i[256];
            float sc6 = m_b / fmaxf(1e-8f, sqrtf(z6r * z6r + z6i * z6i));
            float X6r = z6r * sc6, X6i = -z6i * sc6;
            sm.C1r[256] = X6r * (2.0f / 1024.0f);
            sm.C1i[256] = -X6i * (2.0f / 1024.0f);
        } else {
            float zr = sm.C0r[tid], zi = sm.C0i[tid];
            float ur = sm.C0r[j2],  ui = sm.C0i[j2];
            float er = 0.5f * (zr + ur), ei = 0.5f * (zi - ui);
            float dr = zr - ur,          di = zi + ui;
            float odr = 0.5f * di, odi = -0.5f * dr;
            float e1r = er + w1r_a * odr + w1i_a * odi;
            float e1i = ei + w1r_a * odi - w1i_a * odr;
            float e2r =  er + w1r_b * odr - w1i_b * odi;
            float e2i = -ei - w1r_b * odi - w1i_b * odr;
            float sc1 = m_a / fmaxf(1e-8f, sqrtf(e1r * e1r + e1i * e1i));
            float sc2 = m_b / fmaxf(1e-8f, sqrtf(e2r * e2r + e2i * e2i));
            float X1r = e1r * sc1, X1i = e1i * sc1;
            float X2r = e2r * sc2, X2i = e2i * sc2;
            float Er = X1r + X2r, Ei = X1i - X2i;
            float Dr = X1r - X2r, Di = X1i + X2i;
            float wdr = w1r_a * Dr - w1i_a * Di, wdi = w1r_a * Di + w1i_a * Dr;
            sm.C1r[tid] = (Er - wdi) * (1.0f / 1024.0f);
            sm.C1i[tid] = (Ei + wdr) * (1.0f / 1024.0f);
            float wdr2 = -w1r_b * Dr - w1i_b * Di, wdi2 = w1r_b * Di - w1i_b * Dr;
            sm.C1r[j2] = (Er - wdi2) * (1.0f / 1024.0f);
            sm.C1i[j2] = (-Ei + wdr2) * (1.0f / 1024.0f);
        }
        __syncthreads();

        // inverse FFT: C1 -> C0
        if (tid < 128) {
            float x0r = sm.C1r[tid],       x0i = sm.C1i[tid];
            float x1r = sm.C1r[tid + 128], x1i = sm.C1i[tid + 128];
            float x2r = sm.C1r[tid + 256], x2i = sm.C1i[tid + 256];
            float x3r = sm.C1r[tid + 384], x3i = sm.C1i[tid + 384];
            float t0r = x0r + x2r, t0i = x0i + x2i;
            float t1r = x0r - x2r, t1i = x0i - x2i;
            float t2r = x1r + x3r, t2i = x1i + x3i;
            float t3r = x1r - x3r, t3i = x1i - x3i;
            float4 vr = make_float4(t0r + t2r, t1r - t3i, t0r - t2r, t1r + t3i);
            float4 vi = make_float4(t0i + t2i, t1i + t3r, t0i - t2i, t1i - t3r);
            ((float4*)sm.C0r)[tid] = vr;
            ((float4*)sm.C0i)[tid] = vi;
        }
        __syncthreads();
        if (tid < 128) r4b<4, 5, true>(sm.C0r, sm.C0i, sm.C1r, sm.C1i, sm.twr, sm.twi, tid);
        __syncthreads();
        if (tid < 128) r4b<16, 3, true>(sm.C1r, sm.C1i, sm.C0r, sm.C0i, sm.twr, sm.twi, tid);
        __syncthreads();
        if (tid < 128) r4b<64, 1, true>(sm.C0r, sm.C0i, sm.C1r, sm.C1i, sm.twr, sm.twi, tid);
        __syncthreads();
        {
            float c = sm.twr[tid], s = -sm.twi[tid];
            float x0r = sm.C1r[tid], x0i = sm.C1i[tid];
            float x1r = sm.C1r[tid + 256], x1i = sm.C1i[tid + 256];
            float ar = x1r * c - x1i * s, ai = x1r * s + x1i * c;
            sm.C0r[tid]       = x0r + ar;  sm.C0i[tid]       = x0i + ai;
            sm.C0r[tid + 256] = x0r - ar;  sm.C0i[tid + 256] = x0i - ai;
        }
        __syncthreads();

        // store windowed frame (sc1)
        {
            float4 o;
            o.x = w4.x * sm.C0r[n0];
            o.y = w4.y * sm.C0i[n0];
            o.z = w4.z * sm.C0r[n0 + 1];
            o.w = w4.w * sm.C0i[n0 + 1];
            coh_store4(&F[(t << 10) + i0], o);
        }
        __syncthreads();   // whole block's F stores issued
        // RELEASE: commits all prior sc1 data stores before flag visibility
        if (tid == 0)
            __hip_atomic_store(ffl + t, it, __ATOMIC_RELEASE, __HIP_MEMORY_SCOPE_AGENT);

        // ===== phase B: wait frame^{it} window, OLA own segment(s) =====
        if (tid <= hiB - loB) {
            const int* f = ffl + loB + tid;
            while (__hip_atomic_load(f, __ATOMIC_RELAXED, __HIP_MEMORY_SCOPE_AGENT) < it)
                __builtin_amdgcn_s_sleep(1);
        }
        __syncthreads();   // compiler barrier before F reads

        if (gseg >= 0) {
            float acc = 0.f;
#pragma unroll
            for (int m = 0; m < 16; ++m) {
                int tp = gseg - m;
                if (tp >= 0 && tp < NFR)
                    acc += coh_load1(&F[(tp << 10) + u + (m << 6)]);
            }
            float val = acc * iwreg;
            if (it < NITER) coh_store1(&X[(gseg << 6) + u], val);
            else            out[(gseg << 6) + u] = val;
        }
        __syncthreads();   // block's X stores issued
        if (tid == 0 && it < NITER)
            __hip_atomic_store(sfl + t, it + 1, __ATOMIC_RELEASE, __HIP_MEMORY_SCOPE_AGENT);
    }
}

extern "C" void kernel_launch(void* const* d_in, const int* in_sizes, int n_in,
                              void* d_out, int out_size, void* d_ws, size_t ws_size,
                              hipStream_t stream) {
    const float* mel    = (const float*)d_in[0];
    const float* invmel = (const float*)d_in[1];
    float* out = (float*)d_out;
    float* ws  = (float*)d_ws;

    k_init<<<NFR, NT, 0, stream>>>(mel, invmel, ws);
    k_persist<<<NB, NT, 0, stream>>>(ws, out);
}

// Round 12
// 4634.868 us; speedup vs baseline: 2.8008x; 1.4790x over previous
//
#include <hip/hip_runtime.h>
#include <math.h>

#define NFFT   1024
#define NH     512
#define HOP    64
#define NMELS  80
#define NFR    512
#define NBINS  513
#define NITER  300
#define SIGLEN 33728
#define NTI    256      // k_init block size
#define NTW    64       // k_persist block size (single wave)
#define NB     512

// ---- workspace layout (4B units) ----
#define TBL_WIN  0          // win[1024]
#define TBL_TWR  1024       // twr[256]
#define TBL_TWI  1280       // twi[256]
#define TBL_W1R  1536       // w1r[513]
#define TBL_W1I  2056       // w1i[513]
#define BAR_SLOT 2624       // 512 int slots
#define BAR_GEN  3200       // generation word
#define OFF_MAG  4096       // mag[512*513]
#define OFF_IWS  266752     // iws[33728]
#define OFF_F    300480     // F[512*1024]
#define OFF_X    824768     // x[33792]

typedef unsigned long long u64;
typedef unsigned int u32;

// ---- coherent (agent-scope sc1, L3-point) accessors ----
__device__ __forceinline__ float4 coh_load4(const float* p) {
    u64 a = __hip_atomic_load((const u64*)p,       __ATOMIC_RELAXED, __HIP_MEMORY_SCOPE_AGENT);
    u64 b = __hip_atomic_load((const u64*)(p + 2), __ATOMIC_RELAXED, __HIP_MEMORY_SCOPE_AGENT);
    float2 fa, fb;
    __builtin_memcpy(&fa, &a, 8);
    __builtin_memcpy(&fb, &b, 8);
    return make_float4(fa.x, fa.y, fb.x, fb.y);
}
__device__ __forceinline__ void coh_store4(float* p, float4 v) {
    float2 fa = make_float2(v.x, v.y), fb = make_float2(v.z, v.w);
    u64 a, b;
    __builtin_memcpy(&a, &fa, 8);
    __builtin_memcpy(&b, &fb, 8);
    __hip_atomic_store((u64*)p,       a, __ATOMIC_RELAXED, __HIP_MEMORY_SCOPE_AGENT);
    __hip_atomic_store((u64*)(p + 2), b, __ATOMIC_RELAXED, __HIP_MEMORY_SCOPE_AGENT);
}
__device__ __forceinline__ float coh_load1(const float* p) {
    u32 a = __hip_atomic_load((const u32*)p, __ATOMIC_RELAXED, __HIP_MEMORY_SCOPE_AGENT);
    float f;
    __builtin_memcpy(&f, &a, 4);
    return f;
}
__device__ __forceinline__ void coh_store1(float* p, float v) {
    u32 a;
    __builtin_memcpy(&a, &v, 4);
    __hip_atomic_store((u32*)p, a, __ATOMIC_RELAXED, __HIP_MEMORY_SCOPE_AGENT);
}

// ---- radix-4 Stockham stage (verified), j in [0,128) ----
template<int P, int SH, bool INV>
__device__ __forceinline__ void r4b(const float* __restrict__ sR, const float* __restrict__ sI,
                                    float* __restrict__ dR, float* __restrict__ dI,
                                    const float* twr, const float* twi, int j) {
    int k  = j & (P - 1);
    int d0 = ((j - k) << 2) + k;
    float x0r = sR[j],       x0i = sI[j];
    float x1r = sR[j + 128], x1i = sI[j + 128];
    float x2r = sR[j + 256], x2i = sI[j + 256];
    float x3r = sR[j + 384], x3i = sI[j + 384];
    int tb = k << SH;
    float c1 = twr[tb], s1 = twi[tb];
    if (INV) s1 = -s1;
    float c2 = c1 * c1 - s1 * s1, s2 = 2.f * c1 * s1;
    float c3 = c1 * c2 - s1 * s2, s3 = c1 * s2 + s1 * c2;
    float a1r = x1r * c1 - x1i * s1, a1i = x1r * s1 + x1i * c1;
    float a2r = x2r * c2 - x2i * s2, a2i = x2r * s2 + x2i * c2;
    float a3r = x3r * c3 - x3i * s3, a3i = x3r * s3 + x3i * c3;
    float t0r = x0r + a2r, t0i = x0i + a2i;
    float t1r = x0r - a2r, t1i = x0i - a2i;
    float t2r = a1r + a3r, t2i = a1i + a3i;
    float t3r = a1r - a3r, t3i = a1i - a3i;
    float i3r = INV ? -t3i : t3i;
    float i3i = INV ?  t3r : -t3r;
    dR[d0]         = t0r + t2r;  dI[d0]         = t0i + t2i;
    dR[d0 + P]     = t1r + i3r;  dI[d0 + P]     = t1i + i3i;
    dR[d0 + 2 * P] = t0r - t2r;  dI[d0 + 2 * P] = t0i - t2i;
    dR[d0 + 3 * P] = t1r - i3r;  dI[d0 + 3 * P] = t1i - i3i;
}

// ================= k_init (round-7 verified, unchanged) ======================
struct __align__(16) SMemI {
    float xb[NFFT];
    float C0r[NH], C0i[NH];
    float C1r[NH], C1i[NH];
    float win[NFFT];
    float twr[256], twi[256];
    float mag[516];
};

extern "C" __global__ __launch_bounds__(NTI)
void k_init(const float* __restrict__ mel,
            const float* __restrict__ invmel,
            float* __restrict__ ws) {
    __shared__ SMemI sm;
    const int tid = threadIdx.x;
    const int t   = blockIdx.x;

    for (int n = tid; n < NFFT; n += NTI) {
        double a = (2.0 * 3.14159265358979323846) * (double)n / 1024.0;
        sm.win[n] = (float)(0.5 - 0.5 * cos(a));
    }
    for (int j = tid; j < 256; j += NTI) {
        double a = (2.0 * 3.14159265358979323846) * (double)j / 512.0;
        sm.twr[j] = (float)cos(a);
        sm.twi[j] = (float)(-sin(a));
    }
    __syncthreads();
    if (t == 0) {
        for (int n = tid; n < NFFT; n += NTI) ws[TBL_WIN + n] = sm.win[n];
        for (int j = tid; j < 256; j += NTI) {
            ws[TBL_TWR + j] = sm.twr[j];
            ws[TBL_TWI + j] = sm.twi[j];
        }
        for (int k = tid; k < NBINS; k += NTI) {
            double a = (2.0 * 3.14159265358979323846) * (double)k / 1024.0;
            ws[TBL_W1R + k] = (float)cos(a);
            ws[TBL_W1I + k] = (float)sin(a);
        }
        ((int*)ws)[BAR_SLOT + tid]       = 0;
        ((int*)ws)[BAR_SLOT + 256 + tid] = 0;
        if (tid == 0) ((int*)ws)[BAR_GEN] = 0;
    }

    for (int p = t * NTI + tid; p < SIGLEN; p += NFR * NTI) {
        int tq = p >> 6, io = p & 63;
        float s = 0.f;
#pragma unroll
        for (int m = 0; m < 16; ++m) {
            int tp = tq - m;
            if (tp >= 0 && tp < NFR) {
                float w = sm.win[io + (m << 6)];
                s += w * w;
            }
        }
        ws[OFF_IWS + p] = (s > 1e-11f) ? (1.0f / s) : 1.0f;
    }

    if (tid < NMELS) sm.xb[tid] = exp10f(mel[tid * NFR + t]);
    __syncthreads();
    for (int k = tid; k < NBINS; k += NTI) {
        const float* row = invmel + k * NMELS;
        float s = 0.f;
#pragma unroll 8
        for (int j = 0; j < NMELS; ++j) s += row[j] * sm.xb[j];
        ws[OFF_MAG + t * NBINS + k] = s;
        sm.mag[k] = s;
    }
    __syncthreads();

    for (int k = tid; k < NH; k += NTI) {
        float xr = sm.mag[k], yr = sm.mag[512 - k];
        double a = (2.0 * 3.14159265358979323846) * (double)k / 1024.0;
        float c = (float)cos(a), s = (float)sin(a);
        float dr = xr - yr;
        sm.C1r[k] = ((xr + yr) - s * dr) * (1.0f / 1024.0f);
        sm.C1i[k] = (c * dr) * (1.0f / 1024.0f);
    }
    __syncthreads();
    if (tid < 128) {
        float x0r = sm.C1r[tid],       x0i = sm.C1i[tid];
        float x1r = sm.C1r[tid + 128], x1i = sm.C1i[tid + 128];
        float x2r = sm.C1r[tid + 256], x2i = sm.C1i[tid + 256];
        float x3r = sm.C1r[tid + 384], x3i = sm.C1i[tid + 384];
        float t0r = x0r + x2r, t0i = x0i + x2i;
        float t1r = x0r - x2r, t1i = x0i - x2i;
        float t2r = x1r + x3r, t2i = x1i + x3i;
        float t3r = x1r - x3r, t3i = x1i - x3i;
        float4 vr = make_float4(t0r + t2r, t1r - t3i, t0r - t2r, t1r + t3i);
        float4 vi = make_float4(t0i + t2i, t1i + t3r, t0i - t2i, t1i - t3r);
        ((float4*)sm.C0r)[tid] = vr;
        ((float4*)sm.C0i)[tid] = vi;
    }
    __syncthreads();
    if (tid < 128) r4b<4, 5, true>(sm.C0r, sm.C0i, sm.C1r, sm.C1i, sm.twr, sm.twi, tid);
    __syncthreads();
    if (tid < 128) r4b<16, 3, true>(sm.C1r, sm.C1i, sm.C0r, sm.C0i, sm.twr, sm.twi, tid);
    __syncthreads();
    if (tid < 128) r4b<64, 1, true>(sm.C0r, sm.C0i, sm.C1r, sm.C1i, sm.twr, sm.twi, tid);
    __syncthreads();
    {
        float c = sm.twr[tid], s = -sm.twi[tid];
        float x0r = sm.C1r[tid], x0i = sm.C1i[tid];
        float x1r = sm.C1r[tid + 256], x1i = sm.C1i[tid + 256];
        float ar = x1r * c - x1i * s, ai = x1r * s + x1i * c;
        sm.C0r[tid]       = x0r + ar;  sm.C0i[tid]       = x0i + ai;
        sm.C0r[tid + 256] = x0r - ar;  sm.C0i[tid + 256] = x0i - ai;
    }
    __syncthreads();

    float4 w4 = ((float4*)sm.win)[tid];
    float4 o;
    o.x = w4.x * sm.C0r[2 * tid];
    o.y = w4.y * sm.C0i[2 * tid];
    o.z = w4.z * sm.C0r[2 * tid + 1];
    o.w = w4.w * sm.C0i[2 * tid + 1];
    *(float4*)&ws[OFF_F + (t << 10) + (tid << 2)] = o;
}

// ====== persistent Griffin-Lim: single-wave blocks, round-7 global barrier ==
struct __align__(16) SMW {
    float C0r[NH], C0i[NH];
    float C1r[NH], C1i[NH];
    float twr[256], twi[256];
    float win[NFFT];
    float mag[520], w1r[520], w1i[520];
};

// two-hop global barrier (round-7 semantics; relaxed sc1 stores/loads).
// block0: 64 lanes each re-poll 8 slots per trip (all issued before check).
__device__ __forceinline__ void gbar(int* bar, int t, int l, int bc) {
    __syncthreads();   // single wave: compiles to waitcnt drain (vm+lgkm)
    if (l == 0)
        __hip_atomic_store(bar + BAR_SLOT + t, bc,
                           __ATOMIC_RELAXED, __HIP_MEMORY_SCOPE_AGENT);
    if (t == 0) {
        const int* base = bar + BAR_SLOT + (l << 3);
        for (;;) {
            int a0 = __hip_atomic_load(base + 0, __ATOMIC_RELAXED, __HIP_MEMORY_SCOPE_AGENT);
            int a1 = __hip_atomic_load(base + 1, __ATOMIC_RELAXED, __HIP_MEMORY_SCOPE_AGENT);
            int a2 = __hip_atomic_load(base + 2, __ATOMIC_RELAXED, __HIP_MEMORY_SCOPE_AGENT);
            int a3 = __hip_atomic_load(base + 3, __ATOMIC_RELAXED, __HIP_MEMORY_SCOPE_AGENT);
            int a4 = __hip_atomic_load(base + 4, __ATOMIC_RELAXED, __HIP_MEMORY_SCOPE_AGENT);
            int a5 = __hip_atomic_load(base + 5, __ATOMIC_RELAXED, __HIP_MEMORY_SCOPE_AGENT);
            int a6 = __hip_atomic_load(base + 6, __ATOMIC_RELAXED, __HIP_MEMORY_SCOPE_AGENT);
            int a7 = __hip_atomic_load(base + 7, __ATOMIC_RELAXED, __HIP_MEMORY_SCOPE_AGENT);
            int m01 = a0 < a1 ? a0 : a1;
            int m23 = a2 < a3 ? a2 : a3;
            int m45 = a4 < a5 ? a4 : a5;
            int m67 = a6 < a7 ? a6 : a7;
            int m03 = m01 < m23 ? m01 : m23;
            int m47 = m45 < m67 ? m45 : m67;
            int mn  = m03 < m47 ? m03 : m47;
            if (mn >= bc) break;
            __builtin_amdgcn_s_sleep(1);
        }
        __syncthreads();
        if (l == 0)
            __hip_atomic_store(bar + BAR_GEN, bc,
                               __ATOMIC_RELAXED, __HIP_MEMORY_SCOPE_AGENT);
    }
    if (l == 0) {
        while (__hip_atomic_load(bar + BAR_GEN,
                                 __ATOMIC_RELAXED, __HIP_MEMORY_SCOPE_AGENT) < bc)
            __builtin_amdgcn_s_sleep(2);
    }
    __syncthreads();
}

extern "C" __global__ __launch_bounds__(NTW)
void k_persist(float* __restrict__ ws, float* __restrict__ out) {
    __shared__ SMW sm;
    const int l = threadIdx.x;        // 0..63
    const int t = blockIdx.x;         // frame owned

    const float* tbl  = ws;
    const float* magg = ws + OFF_MAG;
    const float* iws  = ws + OFF_IWS;
    float* F  = ws + OFF_F;
    float* X  = ws + OFF_X;
    int*   bar = (int*)ws;

    // ---- one-time staging into LDS ----
    ((float4*)sm.twr)[l] = ((const float4*)(tbl + TBL_TWR))[l];
    ((float4*)sm.twi)[l] = ((const float4*)(tbl + TBL_TWI))[l];
#pragma unroll
    for (int c = 0; c < 4; ++c)
        ((float4*)sm.win)[l + (c << 6)] = ((const float4*)(tbl + TBL_WIN))[l + (c << 6)];
    for (int k = l; k < NBINS; k += NTW) {
        sm.mag[k] = magg[t * NBINS + k];
        sm.w1r[k] = tbl[TBL_W1R + k];
        sm.w1i[k] = tbl[TBL_W1I + k];
    }
    const bool extra = (t >= 497);
    float iw0 = iws[(t << 6) + l];
    float iw1 = extra ? iws[((t + 15) << 6) + l] : 0.f;
    __syncthreads();

    // ---- prologue: x^0 segment(s) from k_init frames ----
    {
        float acc = 0.f;
#pragma unroll
        for (int m = 0; m < 16; ++m) {
            int tp = t - m;
            if (tp >= 0 && tp < NFR)
                acc += coh_load1(&F[(tp << 10) + l + (m << 6)]);
        }
        coh_store1(&X[(t << 6) + l], acc * iw0);
        if (extra) {
            int g = t + 15;
            float acc2 = 0.f;
#pragma unroll
            for (int m = 0; m < 16; ++m) {
                int tp = g - m;
                if (tp >= 0 && tp < NFR)
                    acc2 += coh_load1(&F[(tp << 10) + l + (m << 6)]);
            }
            coh_store1(&X[(g << 6) + l], acc2 * iw1);
        }
    }
    gbar(bar, t, l, 1);

    int bc = 2;
#pragma unroll 1
    for (int it = 1; it <= NITER; ++it) {
        // ===== phase A: X window -> fwd FFT -> projection -> inv FFT -> F =====
        // gather X * win -> packed z in C1 (chunks over tid' = l+64c)
#pragma unroll
        for (int c = 0; c < 4; ++c) {
            int tp = l + (c << 6);
            int i0 = tp << 2;
            float4 xv = coh_load4(&X[(t << 6) + i0]);
            float4 wv = ((float4*)sm.win)[tp];
            int n0 = tp << 1;
            sm.C1r[n0]     = xv.x * wv.x;
            sm.C1i[n0]     = xv.y * wv.y;
            sm.C1r[n0 + 1] = xv.z * wv.z;
            sm.C1i[n0 + 1] = xv.w * wv.w;
        }
        __syncthreads();
        // fwd stage0: C1 -> C0 (j = l, l+64)
#pragma unroll
        for (int c = 0; c < 2; ++c) {
            int j = l + (c << 6);
            float x0r = sm.C1r[j],       x0i = sm.C1i[j];
            float x1r = sm.C1r[j + 128], x1i = sm.C1i[j + 128];
            float x2r = sm.C1r[j + 256], x2i = sm.C1i[j + 256];
            float x3r = sm.C1r[j + 384], x3i = sm.C1i[j + 384];
            float t0r = x0r + x2r, t0i = x0i + x2i;
            float t1r = x0r - x2r, t1i = x0i - x2i;
            float t2r = x1r + x3r, t2i = x1i + x3i;
            float t3r = x1r - x3r, t3i = x1i - x3i;
            float4 vr = make_float4(t0r + t2r, t1r + t3i, t0r - t2r, t1r - t3i);
            float4 vi = make_float4(t0i + t2i, t1i - t3r, t0i - t2i, t1i + t3r);
            ((float4*)sm.C0r)[j] = vr;
            ((float4*)sm.C0i)[j] = vi;
        }
        __syncthreads();
        r4b<4, 5, false>(sm.C0r, sm.C0i, sm.C1r, sm.C1i, sm.twr, sm.twi, l);
        r4b<4, 5, false>(sm.C0r, sm.C0i, sm.C1r, sm.C1i, sm.twr, sm.twi, l + 64);
        __syncthreads();
        r4b<16, 3, false>(sm.C1r, sm.C1i, sm.C0r, sm.C0i, sm.twr, sm.twi, l);
        r4b<16, 3, false>(sm.C1r, sm.C1i, sm.C0r, sm.C0i, sm.twr, sm.twi, l + 64);
        __syncthreads();
        r4b<64, 1, false>(sm.C0r, sm.C0i, sm.C1r, sm.C1i, sm.twr, sm.twi, l);
        r4b<64, 1, false>(sm.C0r, sm.C0i, sm.C1r, sm.C1i, sm.twr, sm.twi, l + 64);
        __syncthreads();
        // final r2 fwd: C1 -> C0 (chunks tid' = l+64c)
#pragma unroll
        for (int c = 0; c < 4; ++c) {
            int tp = l + (c << 6);
            float cc = sm.twr[tp], s = sm.twi[tp];
            float x0r = sm.C1r[tp], x0i = sm.C1i[tp];
            float x1r = sm.C1r[tp + 256], x1i = sm.C1i[tp + 256];
            float ar = x1r * cc - x1i * s, ai = x1r * s + x1i * cc;
            sm.C0r[tp]       = x0r + ar;  sm.C0i[tp]       = x0i + ai;
            sm.C0r[tp + 256] = x0r - ar;  sm.C0i[tp + 256] = x0i - ai;
        }
        __syncthreads();
        // fused unpack + phase projection + iFFT prep: C0 -> C1
#pragma unroll
        for (int c = 0; c < 4; ++c) {
            int tp = l + (c << 6);
            if (tp == 0) {
                float zr = sm.C0r[0], zi = sm.C0i[0];
                float e0 = zr + zi;
                float e5 = zr - zi;
                float X0 = sm.mag[0]   * e0 / fmaxf(1e-8f, fabsf(e0));
                float X5 = sm.mag[512] * e5 / fmaxf(1e-8f, fabsf(e5));
                sm.C1r[0] = (X0 + X5) * (1.0f / 1024.0f);
                sm.C1i[0] = (X0 - X5) * (1.0f / 1024.0f);
                float z6r = sm.C0r[256], z6i = sm.C0i[256];
                float sc6 = sm.mag[256] / fmaxf(1e-8f, sqrtf(z6r * z6r + z6i * z6i));
                float X6r = z6r * sc6, X6i = -z6i * sc6;
                sm.C1r[256] = X6r * (2.0f / 1024.0f);
                sm.C1i[256] = -X6i * (2.0f / 1024.0f);
            } else {
                int j2 = 512 - tp;
                float m_a = sm.mag[tp], m_b = sm.mag[j2];
                float w1r_a = sm.w1r[tp], w1i_a = sm.w1i[tp];
                float w1r_b = sm.w1r[j2], w1i_b = sm.w1i[j2];
                float zr = sm.C0r[tp], zi = sm.C0i[tp];
                float ur = sm.C0r[j2], ui = sm.C0i[j2];
                float er = 0.5f * (zr + ur), ei = 0.5f * (zi - ui);
                float dr = zr - ur,          di = zi + ui;
                float odr = 0.5f * di, odi = -0.5f * dr;
                float e1r = er + w1r_a * odr + w1i_a * odi;
                float e1i = ei + w1r_a * odi - w1i_a * odr;
                float e2r =  er + w1r_b * odr - w1i_b * odi;
                float e2i = -ei - w1r_b * odi - w1i_b * odr;
                float sc1 = m_a / fmaxf(1e-8f, sqrtf(e1r * e1r + e1i * e1i));
                float sc2 = m_b / fmaxf(1e-8f, sqrtf(e2r * e2r + e2i * e2i));
                float X1r = e1r * sc1, X1i = e1i * sc1;
                float X2r = e2r * sc2, X2i = e2i * sc2;
                float Er = X1r + X2r, Ei = X1i - X2i;
                float Dr = X1r - X2r, Di = X1i + X2i;
                float wdr = w1r_a * Dr - w1i_a * Di, wdi = w1r_a * Di + w1i_a * Dr;
                sm.C1r[tp] = (Er - wdi) * (1.0f / 1024.0f);
                sm.C1i[tp] = (Ei + wdr) * (1.0f / 1024.0f);
                float wdr2 = -w1r_b * Dr - w1i_b * Di, wdi2 = w1r_b * Di - w1i_b * Dr;
                sm.C1r[j2] = (Er - wdi2) * (1.0f / 1024.0f);
                sm.C1i[j2] = (-Ei + wdr2) * (1.0f / 1024.0f);
            }
        }
        __syncthreads();
        // inv stage0: C1 -> C0 (j = l, l+64)
#pragma unroll
        for (int c = 0; c < 2; ++c) {
            int j = l + (c << 6);
            float x0r = sm.C1r[j],       x0i = sm.C1i[j];
            float x1r = sm.C1r[j + 128], x1i = sm.C1i[j + 128];
            float x2r = sm.C1r[j + 256], x2i = sm.C1i[j + 256];
            float x3r = sm.C1r[j + 384], x3i = sm.C1i[j + 384];
            float t0r = x0r + x2r, t0i = x0i + x2i;
            float t1r = x0r - x2r, t1i = x0i - x2i;
            float t2r = x1r + x3r, t2i = x1i + x3i;
            float t3r = x1r - x3r, t3i = x1i - x3i;
            float4 vr = make_float4(t0r + t2r, t1r - t3i, t0r - t2r, t1r + t3i);
            float4 vi = make_float4(t0i + t2i, t1i + t3r, t0i - t2i, t1i - t3r);
            ((float4*)sm.C0r)[j] = vr;
            ((float4*)sm.C0i)[j] = vi;
        }
        __syncthreads();
        r4b<4, 5, true>(sm.C0r, sm.C0i, sm.C1r, sm.C1i, sm.twr, sm.twi, l);
        r4b<4, 5, true>(sm.C0r, sm.C0i, sm.C1r, sm.C1i, sm.twr, sm.twi, l + 64);
        __syncthreads();
        r4b<16, 3, true>(sm.C1r, sm.C1i, sm.C0r, sm.C0i, sm.twr, sm.twi, l);
        r4b<16, 3, true>(sm.C1r, sm.C1i, sm.C0r, sm.C0i, sm.twr, sm.twi, l + 64);
        __syncthreads();
        r4b<64, 1, true>(sm.C0r, sm.C0i, sm.C1r, sm.C1i, sm.twr, sm.twi, l);
        r4b<64, 1, true>(sm.C0r, sm.C0i, sm.C1r, sm.C1i, sm.twr, sm.twi, l + 64);
        __syncthreads();
        // final r2 inv: C1 -> C0 (chunks)
#pragma unroll
        for (int c = 0; c < 4; ++c) {
            int tp = l + (c << 6);
            float cc = sm.twr[tp], s = -sm.twi[tp];
            float x0r = sm.C1r[tp], x0i = sm.C1i[tp];
            float x1r = sm.C1r[tp + 256], x1i = sm.C1i[tp + 256];
            float ar = x1r * cc - x1i * s, ai = x1r * s + x1i * cc;
            sm.C0r[tp]       = x0r + ar;  sm.C0i[tp]       = x0i + ai;
            sm.C0r[tp + 256] = x0r - ar;  sm.C0i[tp + 256] = x0i - ai;
        }
        __syncthreads();
        // store windowed frame (sc1): chunks tid' = l+64c
#pragma unroll
        for (int c = 0; c < 4; ++c) {
            int tp = l + (c << 6);
            int i0 = tp << 2, n0 = tp << 1;
            float4 wv = ((float4*)sm.win)[tp];
            float4 o;
            o.x = wv.x * sm.C0r[n0];
            o.y = wv.y * sm.C0i[n0];
            o.z = wv.z * sm.C0r[n0 + 1];
            o.w = wv.w * sm.C0i[n0 + 1];
            coh_store4(&F[(t << 10) + i0], o);
        }
        gbar(bar, t, l, bc++);   // F^{it} complete everywhere

        // ===== phase B: OLA own segment(s) =====
        {
            float acc = 0.f;
#pragma unroll
            for (int m = 0; m < 16; ++m) {
                int tp = t - m;
                if (tp >= 0 && tp < NFR)
                    acc += coh_load1(&F[(tp << 10) + l + (m << 6)]);
            }
            float val = acc * iw0;
            if (it < NITER) coh_store1(&X[(t << 6) + l], val);
            else            out[(t << 6) + l] = val;
            if (extra) {
                int g = t + 15;
                float acc2 = 0.f;
#pragma unroll
                for (int m = 0; m < 16; ++m) {
                    int tp = g - m;
                    if (tp >= 0 && tp < NFR)
                        acc2 += coh_load1(&F[(tp << 10) + l + (m << 6)]);
                }
                float val2 = acc2 * iw1;
                if (it < NITER) coh_store1(&X[(g << 6) + l], val2);
                else            out[(g << 6) + l] = val2;
            }
        }
        if (it < NITER)
            gbar(bar, t, l, bc++);   // x^{it} complete everywhere
    }
}

extern "C" void kernel_launch(void* const* d_in, const int* in_sizes, int n_in,
                              void* d_out, int out_size, void* d_ws, size_t ws_size,
                              hipStream_t stream) {
    const float* mel    = (const float*)d_in[0];
    const float* invmel = (const float*)d_in[1];
    float* out = (float*)d_out;
    float* ws  = (float*)d_ws;

    k_init<<<NFR, NTI, 0, stream>>>(mel, invmel, ws);
    k_persist<<<NB, NTW, 0, stream>>>(ws, out);
}